// Round 9
// baseline (133.964 us; speedup 1.0000x reference)
//
#include <hip/hip_runtime.h>
#include <type_traits>

// Soft-DTW (gamma=0.1), normalized, batch 64, len 256, dim 8.
// W-space: W = -R/(gamma*ln2); recurrence W = Dw + logaddexp2(logaddexp2(u,ul), lft).
// logaddexp2(a,b) = max + log2(1+2^-|a-b|); log2(1+t) via A&S 4.1.44 deg-5
// minimax poly for ln(1+t) (|err|<=1e-5 on [0,1]) * LOG2E -> saves 8 v_log_f32/step.
typedef _Float16 h2 __attribute__((ext_vector_type(2)));

static constexpr float K1    = -14.426950408889634074f;   // -1/(gamma*ln2)
static constexpr float M2K1  = 28.853900817779268148f;    // -2*K1
static constexpr float KOUT  = -0.069314718055994530942f; // -gamma*ln2 (R = KOUT*W)
static constexpr float WBIG  = -1.0e30f;                  // boundary (-inf surrogate)
static constexpr float LOG2E = 1.4426950408889634074f;
// A&S 4.1.44: ln(1+x) = x(A1 + x(A2 + x(A3 + x(A4 + x*A5)))), 0<=x<=1, |err|<=1e-5
static constexpr float A1 = 0.99949556f, A2 = -0.49190896f, A3 = 0.28947478f,
                       A4 = -0.13606275f, A5 = 0.03215845f;

// wave_shr:1 via DPP: lane l receives lane l-1's value; lane 0 keeps `fill`. Pure VALU.
__device__ __forceinline__ float dpp_shr1(float v, float fill) {
    int r = __builtin_amdgcn_update_dpp(__float_as_int(fill), __float_as_int(v),
                                        0x138 /*wave_shr:1*/, 0xf, 0xf, false);
    return __int_as_float(r);
}
__device__ __forceinline__ unsigned pack2(float a, float b) {
    h2 p; p[0] = (_Float16)a; p[1] = (_Float16)b;
    return __builtin_bit_cast(unsigned, p);
}
__device__ __forceinline__ float hdot(h2 a, h2 b, float c) {
#if __has_builtin(__builtin_amdgcn_fdot2)
    return __builtin_amdgcn_fdot2(a, b, c, false);
#else
    return fmaf((float)a[1], (float)b[1], fmaf((float)a[0], (float)b[0], c));
#endif
}
// ln(1+t) for t in [0,1] (deg-5 minimax, Horner)
__device__ __forceinline__ float ln1p01(float t) {
    float h = fmaf(t, A5, A4);
    h = fmaf(t, h, A3);
    h = fmaf(t, h, A2);
    h = fmaf(t, h, A1);
    return t * h;
}

__global__ void __attribute__((amdgpu_waves_per_eu(1, 1))) __launch_bounds__(64, 1)
sdtw_kernel(const float* __restrict__ x, const float* __restrict__ y,
            float* __restrict__ out)
{
    const int batch = blockIdx.x;
    const int pair  = blockIdx.y;   // 0: xy, 1: xx, 2: yy
    const int lane  = threadIdx.x;  // lane owns cols 4*lane..4*lane+3

    const float* A  = (pair == 2 ? y : x) + batch * 2048;  // rows side
    const float* Bp = (pair == 1 ? x : y) + batch * 2048;  // cols side

    __shared__ unsigned xHs[4][256];  // f16x2-packed rows (dims 0-1,2-3,4-5,6-7)
    __shared__ float    nxs[256];     // K1*|x_i|^2 from the CONVERTED values

    #pragma unroll
    for (int rr = 0; rr < 4; ++rr) {
        int r = lane + rr * 64;
        float4 a0 = *reinterpret_cast<const float4*>(A + r * 8);
        float4 a1 = *reinterpret_cast<const float4*>(A + r * 8 + 4);
        unsigned u0 = pack2(a0.x, a0.y), u1 = pack2(a0.z, a0.w);
        unsigned u2 = pack2(a1.x, a1.y), u3 = pack2(a1.z, a1.w);
        xHs[0][r] = u0; xHs[1][r] = u1; xHs[2][r] = u2; xHs[3][r] = u3;
        h2 h0 = __builtin_bit_cast(h2, u0), h1 = __builtin_bit_cast(h2, u1);
        h2 h2v = __builtin_bit_cast(h2, u2), h3 = __builtin_bit_cast(h2, u3);
        nxs[r] = K1 * hdot(h3, h3, hdot(h2v, h2v, hdot(h1, h1, hdot(h0, h0, 0.0f))));
    }

    // col side: 4 columns x 8 dims as f16x2 in registers
    h2 bh[4][4]; float Knb[4];
    #pragma unroll
    for (int cc = 0; cc < 4; ++cc) {
        const float* bp = Bp + (4 * lane + cc) * 8;
        float4 b0 = *reinterpret_cast<const float4*>(bp);
        float4 b1 = *reinterpret_cast<const float4*>(bp + 4);
        bh[cc][0] = __builtin_bit_cast(h2, pack2(b0.x, b0.y));
        bh[cc][1] = __builtin_bit_cast(h2, pack2(b0.z, b0.w));
        bh[cc][2] = __builtin_bit_cast(h2, pack2(b1.x, b1.y));
        bh[cc][3] = __builtin_bit_cast(h2, pack2(b1.z, b1.w));
        float nb = hdot(bh[cc][3], bh[cc][3], hdot(bh[cc][2], bh[cc][2],
                   hdot(bh[cc][1], bh[cc][1], hdot(bh[cc][0], bh[cc][0], 0.0f))));
        Knb[cc] = K1 * nb;
    }

    __syncthreads();

    float up[4] = {WBIG, WBIG, WBIG, WBIG};   // W[i-1][4l+cc]
    float own_last  = WBIG;                   // W[i_prev][4l+3]
    float left_prev = (lane == 0) ? 0.0f : WBIG;  // lane0 s=0 upleft = R[-1][-1] = 0

    unsigned xc[4], xn[4]; float nxc, nxn;
    xc[0]=xHs[0][0]; xc[1]=xHs[1][0]; xc[2]=xHs[2][0]; xc[3]=xHs[3][0]; nxc=nxs[0];

    auto step = [&](auto phc, int s, unsigned (&XC)[4], float& NXC,
                    unsigned (&XN)[4], float& NXN) {
        constexpr int PH = decltype(phc)::value;  // 0=ramp-up, 1=steady, 2=ramp-down
        // prefetch next row (off critical chain)
        int ipf = s + 1 - lane;
        ipf = ipf < 0 ? 0 : (ipf > 255 ? 255 : ipf);
        XN[0]=xHs[0][ipf]; XN[1]=xHs[1][ipf]; XN[2]=xHs[2][ipf]; XN[3]=xHs[3][ipf];
        NXN = nxs[ipf];

        float lin  = dpp_shr1(own_last, WBIG);  // lane l-1 last-col, step s-1 -> left
        float ulin = left_prev;                 // lane l-1 last-col, step s-2 -> upleft
        left_prev  = lin;

        const int i = s - lane;
        bool act = (PH == 0) ? (i >= 0) : (PH == 2) ? (i < 256) : true;
        if (act) {
            float u0=up[0], u1=up[1], u2=up[2], u3=up[3];
            float ulc = ulin;
            if (PH == 0) {
                if (i == 0) { u0=u1=u2=u3=WBIG; if (lane) ulc = WBIG; }
            }
            const float uu [4] = {u0, u1, u2, u3};
            const float uls[4] = {ulc, u0, u1, u2};

            // distances via f16 dot2 (off-chain); norms pre-scaled by K1
            float Dw[4], a2[4], Dwa2[4];
            h2 xv0 = __builtin_bit_cast(h2, XC[0]);
            h2 xv1 = __builtin_bit_cast(h2, XC[1]);
            h2 xv2 = __builtin_bit_cast(h2, XC[2]);
            h2 xv3 = __builtin_bit_cast(h2, XC[3]);
            #pragma unroll
            for (int cc = 0; cc < 4; ++cc) {
                float dot = hdot(xv3, bh[cc][3], hdot(xv2, bh[cc][2],
                            hdot(xv1, bh[cc][1], hdot(xv0, bh[cc][0], 0.0f))));
                Dw[cc] = fmaf(M2K1, dot, NXC + Knb[cc]);
            }
            // off-chain pair reduce: a2 = logaddexp2(u, ul) (poly log)
            #pragma unroll
            for (int cc = 0; cc < 4; ++cc) {
                float d2 = uu[cc] - uls[cc];
                float m2 = fmaxf(uu[cc], uls[cc]);
                float t  = __builtin_amdgcn_exp2f(-fabsf(d2));
                float a  = fmaf(LOG2E, ln1p01(t), m2);
                a2[cc]   = a;
                Dwa2[cc] = Dw[cc] + a;
            }
            // serial chain: per cell sub -> exp2 -> poly -> fma
            float lft = lin;
            #pragma unroll
            for (int cc = 0; cc < 4; ++cc) {
                float q   = Dw[cc] + lft;
                float dlt = a2[cc] - lft;
                float t2  = __builtin_amdgcn_exp2f(-fabsf(dlt));
                float mx  = fmaxf(Dwa2[cc], q);        // = Dw + max(a2, lft)
                float w   = fmaf(LOG2E, ln1p01(t2), mx);
                up[cc] = w;
                lft    = w;
            }
            own_last = lft;
        }
    };

    std::integral_constant<int,0> P0; std::integral_constant<int,1> P1;
    std::integral_constant<int,2> P2;
    for (int s = 0;   s < 64;  s += 2) { step(P0, s, xc, nxc, xn, nxn); step(P0, s+1, xn, nxn, xc, nxc); }
    for (int s = 64;  s < 256; s += 2) { step(P1, s, xc, nxc, xn, nxn); step(P1, s+1, xn, nxn, xc, nxc); }
    for (int s = 256; s < 320; s += 2) { step(P2, s, xc, nxc, xn, nxn); step(P2, s+1, xn, nxn, xc, nxc); }

    if (lane == 63) {
        float r   = own_last * KOUT;                     // back to R-space
        float wgt = (pair == 0) ? (1.0f / 64.0f) : (-0.5f / 64.0f);
        atomicAdd(out, r * wgt);
    }
}

extern "C" void kernel_launch(void* const* d_in, const int* in_sizes, int n_in,
                              void* d_out, int out_size, void* d_ws, size_t ws_size,
                              hipStream_t stream)
{
    const float* x = (const float*)d_in[0];
    const float* y = (const float*)d_in[1];
    float* out = (float*)d_out;

    hipMemsetAsync(out, 0, out_size * sizeof(float), stream);
    hipLaunchKernelGGL(sdtw_kernel, dim3(64, 3), dim3(64), 0, stream, x, y, out);
}